// Round 2
// baseline (338.788 us; speedup 1.0000x reference)
//
#include <hip/hip_runtime.h>

// Problem constants (GlobalPointer: B=16, L=512, H=1024, HEADS=12, D=64)
#define BB 16
#define LL 512
#define HH 1024
#define HEADS 12
#define DD 64
#define N1 1536   // HEADS * 2 * DD
#define M1 8192   // BB * LL
#define NEGC 1e12f

typedef short bf16x8 __attribute__((ext_vector_type(8)));
typedef float f32x4 __attribute__((ext_vector_type(4)));

typedef const __attribute__((address_space(1))) void* as1cvp;
typedef __attribute__((address_space(3))) void* as3vp;

__device__ __forceinline__ unsigned short f2bf(float f) {
    union { float f; unsigned int u; } v; v.f = f;
    unsigned int u = v.u;
    return (unsigned short)((u + 0x7fffu + ((u >> 16) & 1u)) >> 16);
}

// async global -> LDS, 16B per lane; lds dest = wave-uniform base + lane*16
__device__ __forceinline__ void gl_lds16(const void* g, void* l) {
    __builtin_amdgcn_global_load_lds((as1cvp)g, (as3vp)l, 16, 0, 0);
}

// ---------------- Kernel 1 (fused prep): X->bf16  +  W transpose->bf16 ----------------
// blocks [0, 8192): convert X (8192*1024 fp32, 4 elems/thread)
// blocks [8192, 9728): transpose W 32x32 tiles (48 n-blocks x 32 k-blocks)
__global__ __launch_bounds__(256) void k_prep(const float* __restrict__ X,
                                              unsigned short* __restrict__ Xb,
                                              const float* __restrict__ W,
                                              unsigned short* __restrict__ Wt) {
    __shared__ float tile[32][33];
    int blk = blockIdx.x;
    int tid = threadIdx.x;
    if (blk < 8192) {
        int i = blk * 256 + tid;          // exactly M1*HH/4 = 8192*256
        float4 v = ((const float4*)X)[i];
        ushort4 o;
        o.x = f2bf(v.x); o.y = f2bf(v.y); o.z = f2bf(v.z); o.w = f2bf(v.w);
        ((ushort4*)Xb)[i] = o;
    } else {
        int bi = blk - 8192;              // 0..1535
        int n0 = (bi % 48) * 32;
        int k0 = (bi / 48) * 32;
        int tx = tid & 31;                // 0..31
        int ty = tid >> 5;                // 0..7
#pragma unroll
        for (int i = 0; i < 4; i++) {
            int k = ty + i * 8;
            tile[k][tx] = W[(size_t)(k0 + k) * N1 + n0 + tx];
        }
        __syncthreads();
#pragma unroll
        for (int i = 0; i < 4; i++) {
            int n = ty + i * 8;
            Wt[(size_t)(n0 + n) * HH + k0 + tx] = f2bf(tile[tx][n]);
        }
    }
}

// ------------- Kernel 2: C = Xb @ Wt^T (+bias, RoPE) -> Qr, Kr (bf16) -------------
// m97 structure: 128x128 tile, BK=32, 256 threads = 4 waves (2x2), each wave 64x64
// = 4x4 MFMA 16x16x32 tiles. Staging via global_load_lds width 16 (linear LDS).
// SWAPPED operands: acc[ni][mi] = mfma(b[ni], a[mi]) so D row (lq*4+r) = n,
// D col (lane&15) = m -> each lane holds 4 consecutive channels: in-register RoPE
// pairs (no shfl), float4 pe/bias loads, ushort4 stores.
__global__ __launch_bounds__(256) void k_gemm1_rope(
    const unsigned short* __restrict__ Xb,   // [8192][1024]
    const unsigned short* __restrict__ Wt,   // [1536][1024]
    const float* __restrict__ bias,          // [1536]
    const float* __restrict__ pe,            // [512][64]  pe[l][2i]=sin, [2i+1]=cos
    unsigned short* __restrict__ Qr,         // [B*HEADS*512][64]
    unsigned short* __restrict__ Kr)
{
    __shared__ __align__(16) unsigned short As[128 * 32];  // 8 KB, linear [row][32]
    __shared__ __align__(16) unsigned short Bs[128 * 32];  // 8 KB
    int m0 = blockIdx.y * 128;
    int n0 = blockIdx.x * 128;
    int tid = threadIdx.x;
    int w  = tid >> 6;
    int ln = tid & 63;
    int lq = ln >> 4;
    int lm = ln & 15;
    int wm = (w & 1) * 64;
    int wn = (w >> 1) * 64;

    // staging: thread covers byte tid*16 (+4096 for second half) of each 8KB tile
    int srow = tid >> 2;            // 0..63
    int scol = (tid & 3) * 8;       // 0,8,16,24
    const unsigned short* ga0 = &Xb[(size_t)(m0 + srow) * HH + scol];
    const unsigned short* ga1 = &Xb[(size_t)(m0 + 64 + srow) * HH + scol];
    const unsigned short* gb0 = &Wt[(size_t)(n0 + srow) * HH + scol];
    const unsigned short* gb1 = &Wt[(size_t)(n0 + 64 + srow) * HH + scol];
    unsigned short* la = &As[w * 512];          // wave-uniform base (w*1024 bytes)
    unsigned short* lb = &Bs[w * 512];

    f32x4 acc[4][4] = {};   // [ni][mi]

    for (int kk = 0; kk < HH; kk += 32) {
        gl_lds16(ga0 + kk, la);
        gl_lds16(ga1 + kk, la + 2048);
        gl_lds16(gb0 + kk, lb);
        gl_lds16(gb1 + kk, lb + 2048);
        __syncthreads();   // drains vmcnt (global_load_lds) before ds_read

        bf16x8 a[4], b[4];
#pragma unroll
        for (int i = 0; i < 4; i++) {
            a[i] = *(const bf16x8*)&As[(wm + i * 16 + lm) * 32 + lq * 8];
            b[i] = *(const bf16x8*)&Bs[(wn + i * 16 + lm) * 32 + lq * 8];
        }
#pragma unroll
        for (int ni = 0; ni < 4; ni++)
#pragma unroll
            for (int mi = 0; mi < 4; mi++)
                acc[ni][mi] = __builtin_amdgcn_mfma_f32_16x16x32_bf16(
                    b[ni], a[mi], acc[ni][mi], 0, 0, 0);
        __syncthreads();   // frags consumed before next-tile overwrite
    }

    // Epilogue: bias + interleaved RoPE fully in-register, vectorized stores.
#pragma unroll
    for (int ni = 0; ni < 4; ni++) {
        int nb = n0 + wn + ni * 16 + lq * 4;     // 4-aligned channel base
        int h  = nb >> 7;                         // head (uniform over the 4 regs)
        int c  = nb & 127;
        int jb = c & 63;                          // d-index base (even, 4-aligned)
        unsigned short* dst = (c >= 64) ? Kr : Qr;
        float4 bv = *(const float4*)&bias[nb];
#pragma unroll
        for (int mi = 0; mi < 4; mi++) {
            int m = m0 + wm + mi * 16 + lm;       // 0..8191
            int l = m & (LL - 1);
            int bidx = m >> 9;
            float4 sc = *(const float4*)&pe[l * 64 + jb]; // {sin0,cos0,sin1,cos1}
            float v0 = acc[ni][mi][0] + bv.x;
            float v1 = acc[ni][mi][1] + bv.y;
            float v2 = acc[ni][mi][2] + bv.z;
            float v3 = acc[ni][mi][3] + bv.w;
            float o0 = v0 * sc.y - v1 * sc.x;     // even: x*cos - x_odd*sin
            float o1 = v1 * sc.y + v0 * sc.x;     // odd:  x*cos + x_even*sin
            float o2 = v2 * sc.w - v3 * sc.z;
            float o3 = v3 * sc.w + v2 * sc.z;
            ushort4 ov;
            ov.x = f2bf(o0); ov.y = f2bf(o1); ov.z = f2bf(o2); ov.w = f2bf(o3);
            size_t idx = ((size_t)(bidx * HEADS + h) * LL + l) * DD + jb;
            *(ushort4*)&dst[idx] = ov;
        }
    }
}

// ------------- Kernel 3: logits = Q @ K^T, mask, /8 -------------
// Per (b,h): 512x512, K-dim 64. Block 128x128 tile, 4 waves (2x2), NO LDS
// (Q+K per bh = 128 KB, L1/L2-resident). Swapped MFMA: acc = mfma(Kfrag, Qfrag)
// -> D row (lq*4+r) = n, D col (lane&15) = m -> float4 stores along n.
// Fully-causal-masked blocks (n0+127 < m0) skip loads/MFMA: |dot| << ulp(1e12)/2
// so (dot*pm - (1-pm)*NEG - NEG) rounds identically with dot=0.
__global__ __launch_bounds__(256) void k_gemm2(
    const unsigned short* __restrict__ Qr,
    const unsigned short* __restrict__ Kr,
    const int* __restrict__ mask,            // [B][L]
    float* __restrict__ out)                 // [B][HEADS][L][L]
{
    int bh = blockIdx.z;
    int b  = bh / HEADS;
    int n0 = blockIdx.x * 128;
    int m0 = blockIdx.y * 128;
    int tid = threadIdx.x;
    int w  = tid >> 6;
    int ln = tid & 63;
    int lq = ln >> 4;
    int lm = ln & 15;
    int wm = (w & 1) * 64;
    int wn = (w >> 1) * 64;

    const unsigned short* Qb = Qr + (size_t)bh * LL * DD;
    const unsigned short* Kb = Kr + (size_t)bh * LL * DD;

    f32x4 acc[4][4] = {};   // [ni][mi]
    if (n0 + 127 >= m0) {   // tile touches the surviving (n >= m) region
#pragma unroll
        for (int kk = 0; kk < 64; kk += 32) {
            bf16x8 q[4], k[4];
#pragma unroll
            for (int i = 0; i < 4; i++) {
                q[i] = *(const bf16x8*)&Qb[(size_t)(m0 + wm + i * 16 + lm) * DD + kk + lq * 8];
                k[i] = *(const bf16x8*)&Kb[(size_t)(n0 + wn + i * 16 + lm) * DD + kk + lq * 8];
            }
#pragma unroll
            for (int ni = 0; ni < 4; ni++)
#pragma unroll
                for (int mi = 0; mi < 4; mi++)
                    acc[ni][mi] = __builtin_amdgcn_mfma_f32_16x16x32_bf16(
                        k[ni], q[mi], acc[ni][mi], 0, 0, 0);
        }
    }

#pragma unroll
    for (int ni = 0; ni < 4; ni++) {
        int nb = n0 + wn + ni * 16 + lq * 4;            // 4 consecutive n in regs
        int4 mv = *(const int4*)&mask[b * LL + nb];     // 16B-aligned
#pragma unroll
        for (int mi = 0; mi < 4; mi++) {
            int m = m0 + wm + mi * 16 + lm;
            f32x4 o;
#pragma unroll
            for (int r = 0; r < 4; r++) {
                int n = nb + r;
                float pm = (float)((&mv.x)[r]);
                float dot = acc[ni][mi][r];
                o[r] = (dot * pm - (1.0f - pm) * NEGC - (n < m ? NEGC : 0.0f)) * 0.125f;
            }
            *(f32x4*)&out[((size_t)bh * LL + m) * LL + nb] = o;
        }
    }
}

extern "C" void kernel_launch(void* const* d_in, const int* in_sizes, int n_in,
                              void* d_out, int out_size, void* d_ws, size_t ws_size,
                              hipStream_t stream) {
    const float* X    = (const float*)d_in[0];   // (16,512,1024)
    const int*   mask = (const int*)d_in[1];     // (16,512)
    const float* W    = (const float*)d_in[2];   // (1024,1536)
    const float* bias = (const float*)d_in[3];   // (1536,)
    const float* pe   = (const float*)d_in[4];   // (512,64)
    float* out = (float*)d_out;

    char* ws = (char*)d_ws;
    unsigned short* Xb = (unsigned short*)ws;                                // 16.78 MB
    unsigned short* Wt = (unsigned short*)(ws + 16777216);                   // 3.15 MB
    unsigned short* Qr = (unsigned short*)(ws + 16777216 + 3145728);         // 12.58 MB
    unsigned short* Kr = Qr + (size_t)BB * HEADS * LL * DD;                  // 12.58 MB

    // 1) fused prep: convert X + transpose/convert W
    k_prep<<<dim3(8192 + 1536), dim3(256), 0, stream>>>(X, Xb, W, Wt);
    // 2) GEMM1 + bias + RoPE -> Qr, Kr  (128x128 tiles, gload_lds, in-reg RoPE)
    k_gemm1_rope<<<dim3(N1 / 128, M1 / 128), dim3(256), 0, stream>>>(Xb, Wt, bias, pe, Qr, Kr);
    // 3) GEMM2 + mask + scale -> out  (128x128, no-LDS, causal skip, f32x4 stores)
    k_gemm2<<<dim3(LL / 128, LL / 128, BB * HEADS), dim3(256), 0, stream>>>(Qr, Kr, mask, out);
}

// Round 3
// 334.507 us; speedup vs baseline: 1.0128x; 1.0128x over previous
//
#include <hip/hip_runtime.h>

// Problem constants (GlobalPointer: B=16, L=512, H=1024, HEADS=12, D=64)
#define BB 16
#define LL 512
#define HH 1024
#define HEADS 12
#define DD 64
#define N1 1536   // HEADS * 2 * DD
#define M1 8192   // BB * LL
#define NEGC 1e12f

typedef short bf16x8 __attribute__((ext_vector_type(8)));
typedef float f32x4 __attribute__((ext_vector_type(4)));

typedef const __attribute__((address_space(1))) void* as1cvp;
typedef __attribute__((address_space(3))) void* as3vp;

__device__ __forceinline__ unsigned short f2bf(float f) {
    union { float f; unsigned int u; } v; v.f = f;
    unsigned int u = v.u;
    return (unsigned short)((u + 0x7fffu + ((u >> 16) & 1u)) >> 16);
}

// async global -> LDS, 16B per lane; lds dest = wave-uniform base + lane*16
__device__ __forceinline__ void gl_lds16(const void* g, void* l) {
    __builtin_amdgcn_global_load_lds((as1cvp)g, (as3vp)l, 16, 0, 0);
}

// ---------------- Kernel 1 (fused prep): X->bf16  +  W transpose->bf16 ----------------
// blocks [0, 8192): convert X (8192*1024 fp32, 4 elems/thread)
// blocks [8192, 9728): transpose W 32x32 tiles (48 n-blocks x 32 k-blocks)
__global__ __launch_bounds__(256) void k_prep(const float* __restrict__ X,
                                              unsigned short* __restrict__ Xb,
                                              const float* __restrict__ W,
                                              unsigned short* __restrict__ Wt) {
    __shared__ float tile[32][33];
    int blk = blockIdx.x;
    int tid = threadIdx.x;
    if (blk < 8192) {
        int i = blk * 256 + tid;          // exactly M1*HH/4 = 8192*256
        float4 v = ((const float4*)X)[i];
        ushort4 o;
        o.x = f2bf(v.x); o.y = f2bf(v.y); o.z = f2bf(v.z); o.w = f2bf(v.w);
        ((ushort4*)Xb)[i] = o;
    } else {
        int bi = blk - 8192;              // 0..1535
        int n0 = (bi % 48) * 32;
        int k0 = (bi / 48) * 32;
        int tx = tid & 31;                // 0..31
        int ty = tid >> 5;                // 0..7
#pragma unroll
        for (int i = 0; i < 4; i++) {
            int k = ty + i * 8;
            tile[k][tx] = W[(size_t)(k0 + k) * N1 + n0 + tx];
        }
        __syncthreads();
#pragma unroll
        for (int i = 0; i < 4; i++) {
            int n = ty + i * 8;
            Wt[(size_t)(n0 + n) * HH + k0 + tx] = f2bf(tile[tx][n]);
        }
    }
}

// ------------- Kernel 2: C = Xb @ Wt^T (+bias, RoPE) -> Qr, Kr (bf16) -------------
// m97 structure: 128x128 tile, BK=32, 256 threads = 4 waves (2x2), each wave 64x64
// = 4x4 MFMA 16x16x32 tiles. Staging via global_load_lds width 16 (linear LDS).
// NORMAL operand order (round-1-verified, absmax 0.03125): D col=lane&15 -> n,
// D row=(lane>>4)*4+reg -> m; RoPE pairing via shfl_xor over lane bit 0.
// XCD-aware bijective block swizzle: 768 blocks, each XCD gets 96 consecutive
// virtual ids = 8 contiguous m-panels (2MB Xb) + all Wt (3.1MB) ~ fits its 4MB L2.
__global__ __launch_bounds__(256) void k_gemm1_rope(
    const unsigned short* __restrict__ Xb,   // [8192][1024]
    const unsigned short* __restrict__ Wt,   // [1536][1024]
    const float* __restrict__ bias,          // [1536]
    const float* __restrict__ pe,            // [512][64]  pe[l][2i]=sin, [2i+1]=cos
    unsigned short* __restrict__ Qr,         // [B*HEADS*512][64]
    unsigned short* __restrict__ Kr)
{
    __shared__ __align__(16) unsigned short As[128 * 32];  // 8 KB, linear [row][32]
    __shared__ __align__(16) unsigned short Bs[128 * 32];  // 8 KB
    // bijective XCD swizzle (768 = 8 * 96)
    int hwid = blockIdx.x + gridDim.x * blockIdx.y;   // hardware dispatch order
    int vid  = (hwid & 7) * 96 + (hwid >> 3);
    int m0 = (vid / 12) * 128;
    int n0 = (vid % 12) * 128;
    int tid = threadIdx.x;
    int w  = tid >> 6;
    int ln = tid & 63;
    int lq = ln >> 4;
    int lm = ln & 15;
    int wm = (w & 1) * 64;
    int wn = (w >> 1) * 64;

    // staging: thread covers byte tid*16 (+4096 for second half) of each 8KB tile
    int srow = tid >> 2;            // 0..63
    int scol = (tid & 3) * 8;       // 0,8,16,24
    const unsigned short* ga0 = &Xb[(size_t)(m0 + srow) * HH + scol];
    const unsigned short* ga1 = &Xb[(size_t)(m0 + 64 + srow) * HH + scol];
    const unsigned short* gb0 = &Wt[(size_t)(n0 + srow) * HH + scol];
    const unsigned short* gb1 = &Wt[(size_t)(n0 + 64 + srow) * HH + scol];
    unsigned short* la = &As[w * 512];          // wave-uniform base (w*1024 bytes)
    unsigned short* lb = &Bs[w * 512];

    f32x4 acc[4][4] = {};   // [mi][ni]

    for (int kk = 0; kk < HH; kk += 32) {
        gl_lds16(ga0 + kk, la);
        gl_lds16(ga1 + kk, la + 2048);
        gl_lds16(gb0 + kk, lb);
        gl_lds16(gb1 + kk, lb + 2048);
        __syncthreads();   // drains vmcnt (global_load_lds) before ds_read

        bf16x8 a[4], b[4];
#pragma unroll
        for (int i = 0; i < 4; i++) {
            a[i] = *(const bf16x8*)&As[(wm + i * 16 + lm) * 32 + lq * 8];
            b[i] = *(const bf16x8*)&Bs[(wn + i * 16 + lm) * 32 + lq * 8];
        }
#pragma unroll
        for (int mi = 0; mi < 4; mi++)
#pragma unroll
            for (int ni = 0; ni < 4; ni++)
                acc[mi][ni] = __builtin_amdgcn_mfma_f32_16x16x32_bf16(
                    a[mi], b[ni], acc[mi][ni], 0, 0, 0);
        __syncthreads();   // frags consumed before next-tile overwrite
    }

    // Epilogue (round-1-verified): bias + interleaved RoPE via shfl_xor pairing.
#pragma unroll
    for (int ni = 0; ni < 4; ni++) {
        int n = n0 + wn + ni * 16 + lm;         // 0..1535
        float bv = bias[n];
        int h = n >> 7;                          // head
        int c = n & 127;                         // channel in [0,128)
        int j = c & 63;                          // d-index
        int ii = j >> 1;                         // freq index
        bool isK = (c >= 64);
        unsigned short* dst = isK ? Kr : Qr;
#pragma unroll
        for (int mi = 0; mi < 4; mi++) {
#pragma unroll
            for (int r = 0; r < 4; r++) {
                int m = m0 + wm + mi * 16 + lq * 4 + r;   // 0..8191
                int l = m & (LL - 1);
                int bidx = m >> 9;
                float v = acc[mi][ni][r] + bv;
                float vp = __shfl_xor(v, 1, 64);          // partner n^1 == lane^1
                float2 sc = *(const float2*)&pe[l * 64 + 2 * ii]; // {sin, cos}
                float o = (j & 1) ? (v * sc.y + vp * sc.x) : (v * sc.y - vp * sc.x);
                size_t idx = ((size_t)(bidx * HEADS + h) * LL + l) * DD + j;
                dst[idx] = f2bf(o);
            }
        }
    }
}

// ------------- Kernel 3: logits = Q @ K^T, mask, /8 -------------
// Per (b,h): 512x512, K-dim 64. Block 128x128 tile, 4 waves (2x2), NO LDS
// (Q+K per bh = 128 KB, L1/L2-resident). Swapped MFMA: acc = mfma(Kfrag, Qfrag)
// -> D row (lq*4+r) = n, D col (lane&15) = m -> float4 stores along n.
// Fully-causal-masked blocks (n0+127 < m0) skip loads/MFMA: |dot| << ulp(1e12)/2
// so (dot*pm - (1-pm)*NEG - NEG) rounds identically with dot=0.
__global__ __launch_bounds__(256) void k_gemm2(
    const unsigned short* __restrict__ Qr,
    const unsigned short* __restrict__ Kr,
    const int* __restrict__ mask,            // [B][L]
    float* __restrict__ out)                 // [B][HEADS][L][L]
{
    int bh = blockIdx.z;
    int b  = bh / HEADS;
    int n0 = blockIdx.x * 128;
    int m0 = blockIdx.y * 128;
    int tid = threadIdx.x;
    int w  = tid >> 6;
    int ln = tid & 63;
    int lq = ln >> 4;
    int lm = ln & 15;
    int wm = (w & 1) * 64;
    int wn = (w >> 1) * 64;

    const unsigned short* Qb = Qr + (size_t)bh * LL * DD;
    const unsigned short* Kb = Kr + (size_t)bh * LL * DD;

    f32x4 acc[4][4] = {};   // [ni][mi]
    if (n0 + 127 >= m0) {   // tile touches the surviving (n >= m) region
#pragma unroll
        for (int kk = 0; kk < 64; kk += 32) {
            bf16x8 q[4], k[4];
#pragma unroll
            for (int i = 0; i < 4; i++) {
                q[i] = *(const bf16x8*)&Qb[(size_t)(m0 + wm + i * 16 + lm) * DD + kk + lq * 8];
                k[i] = *(const bf16x8*)&Kb[(size_t)(n0 + wn + i * 16 + lm) * DD + kk + lq * 8];
            }
#pragma unroll
            for (int ni = 0; ni < 4; ni++)
#pragma unroll
                for (int mi = 0; mi < 4; mi++)
                    acc[ni][mi] = __builtin_amdgcn_mfma_f32_16x16x32_bf16(
                        k[ni], q[mi], acc[ni][mi], 0, 0, 0);
        }
    }

#pragma unroll
    for (int ni = 0; ni < 4; ni++) {
        int nb = n0 + wn + ni * 16 + lq * 4;            // 4 consecutive n in regs
        int4 mv = *(const int4*)&mask[b * LL + nb];     // 16B-aligned
#pragma unroll
        for (int mi = 0; mi < 4; mi++) {
            int m = m0 + wm + mi * 16 + lm;
            f32x4 o;
#pragma unroll
            for (int r = 0; r < 4; r++) {
                int n = nb + r;
                float pm = (float)((&mv.x)[r]);
                float dot = acc[ni][mi][r];
                o[r] = (dot * pm - (1.0f - pm) * NEGC - (n < m ? NEGC : 0.0f)) * 0.125f;
            }
            *(f32x4*)&out[((size_t)bh * LL + m) * LL + nb] = o;
        }
    }
}

extern "C" void kernel_launch(void* const* d_in, const int* in_sizes, int n_in,
                              void* d_out, int out_size, void* d_ws, size_t ws_size,
                              hipStream_t stream) {
    const float* X    = (const float*)d_in[0];   // (16,512,1024)
    const int*   mask = (const int*)d_in[1];     // (16,512)
    const float* W    = (const float*)d_in[2];   // (1024,1536)
    const float* bias = (const float*)d_in[3];   // (1536,)
    const float* pe   = (const float*)d_in[4];   // (512,64)
    float* out = (float*)d_out;

    char* ws = (char*)d_ws;
    unsigned short* Xb = (unsigned short*)ws;                                // 16.78 MB
    unsigned short* Wt = (unsigned short*)(ws + 16777216);                   // 3.15 MB
    unsigned short* Qr = (unsigned short*)(ws + 16777216 + 3145728);         // 12.58 MB
    unsigned short* Kr = Qr + (size_t)BB * HEADS * LL * DD;                  // 12.58 MB

    // 1) fused prep: convert X + transpose/convert W
    k_prep<<<dim3(8192 + 1536), dim3(256), 0, stream>>>(X, Xb, W, Wt);
    // 2) GEMM1 + bias + RoPE -> Qr, Kr  (128x128, gload_lds, XCD swizzle, shfl RoPE)
    k_gemm1_rope<<<dim3(N1 / 128, M1 / 128), dim3(256), 0, stream>>>(Xb, Wt, bias, pe, Qr, Kr);
    // 3) GEMM2 + mask + scale -> out  (128x128, no-LDS, causal skip, f32x4 stores)
    k_gemm2<<<dim3(LL / 128, LL / 128, BB * HEADS), dim3(256), 0, stream>>>(Qr, Kr, mask, out);
}

// Round 5
// 316.526 us; speedup vs baseline: 1.0703x; 1.0568x over previous
//
#include <hip/hip_runtime.h>

// Problem constants (GlobalPointer: B=16, L=512, H=1024, HEADS=12, D=64)
#define BB 16
#define LL 512
#define HH 1024
#define HEADS 12
#define DD 64
#define N1 1536   // HEADS * 2 * DD
#define M1 8192   // BB * LL
#define NEGC 1e12f

typedef short bf16x8 __attribute__((ext_vector_type(8)));
typedef float f32x4 __attribute__((ext_vector_type(4)));

typedef const __attribute__((address_space(1))) void* as1cvp;
typedef __attribute__((address_space(3))) void* as3vp;

__device__ __forceinline__ unsigned short f2bf(float f) {
    union { float f; unsigned int u; } v; v.f = f;
    unsigned int u = v.u;
    return (unsigned short)((u + 0x7fffu + ((u >> 16) & 1u)) >> 16);
}

// async global -> LDS, 16B per lane; lds dest = wave-uniform base + lane*16
__device__ __forceinline__ void gl_lds16(const void* g, void* l) {
    __builtin_amdgcn_global_load_lds((as1cvp)g, (as3vp)l, 16, 0, 0);
}

// ---------------- Kernel 1 (fused prep): X->bf16  +  W transpose->bf16 ----------------
// blocks [0, 8192): convert X (8192*1024 fp32, 4 elems/thread)
// blocks [8192, 9728): transpose W 32x32 tiles (48 n-blocks x 32 k-blocks)
__global__ __launch_bounds__(256) void k_prep(const float* __restrict__ X,
                                              unsigned short* __restrict__ Xb,
                                              const float* __restrict__ W,
                                              unsigned short* __restrict__ Wt) {
    __shared__ float tile[32][33];
    int blk = blockIdx.x;
    int tid = threadIdx.x;
    if (blk < 8192) {
        int i = blk * 256 + tid;          // exactly M1*HH/4 = 8192*256
        float4 v = ((const float4*)X)[i];
        ushort4 o;
        o.x = f2bf(v.x); o.y = f2bf(v.y); o.z = f2bf(v.z); o.w = f2bf(v.w);
        ((ushort4*)Xb)[i] = o;
    } else {
        int bi = blk - 8192;              // 0..1535
        int n0 = (bi % 48) * 32;
        int k0 = (bi / 48) * 32;
        int tx = tid & 31;                // 0..31
        int ty = tid >> 5;                // 0..7
#pragma unroll
        for (int i = 0; i < 4; i++) {
            int k = ty + i * 8;
            tile[k][tx] = W[(size_t)(k0 + k) * N1 + n0 + tx];
        }
        __syncthreads();
#pragma unroll
        for (int i = 0; i < 4; i++) {
            int n = ty + i * 8;
            Wt[(size_t)(n0 + n) * HH + k0 + tx] = f2bf(tile[tx][n]);
        }
    }
}

// ------------- Kernel 2: C = Xb @ Wt^T (+bias, RoPE) -> Qr, Kr (bf16) -------------
// m97 structure: 128x128 tile, BK=32, 256 threads = 4 waves (2x2), each wave 64x64
// = 4x4 MFMA 16x16x32 tiles. Staging via global_load_lds width 16 (linear LDS).
// NORMAL operand order (round-1/3-verified, absmax 0.03125): D col=lane&15 -> n,
// D row=(lane>>4)*4+reg -> m; RoPE pairing via shfl_xor over lane bit 0.
// XCD-aware bijective block swizzle: 768 = 8 * 96.
__global__ __launch_bounds__(256) void k_gemm1_rope(
    const unsigned short* __restrict__ Xb,   // [8192][1024]
    const unsigned short* __restrict__ Wt,   // [1536][1024]
    const float* __restrict__ bias,          // [1536]
    const float* __restrict__ pe,            // [512][64]  pe[l][2i]=sin, [2i+1]=cos
    unsigned short* __restrict__ Qr,         // [B*HEADS*512][64]
    unsigned short* __restrict__ Kr)
{
    __shared__ __align__(16) unsigned short As[128 * 32];  // 8 KB, linear [row][32]
    __shared__ __align__(16) unsigned short Bs[128 * 32];  // 8 KB
    // bijective XCD swizzle (768 = 8 * 96)
    int hwid = blockIdx.x + gridDim.x * blockIdx.y;   // hardware dispatch order
    int vid  = (hwid & 7) * 96 + (hwid >> 3);
    int m0 = (vid / 12) * 128;
    int n0 = (vid % 12) * 128;
    int tid = threadIdx.x;
    int w  = tid >> 6;
    int ln = tid & 63;
    int lq = ln >> 4;
    int lm = ln & 15;
    int wm = (w & 1) * 64;
    int wn = (w >> 1) * 64;

    // staging: thread covers byte tid*16 (+4096 for second half) of each 8KB tile
    int srow = tid >> 2;            // 0..63
    int scol = (tid & 3) * 8;       // 0,8,16,24
    const unsigned short* ga0 = &Xb[(size_t)(m0 + srow) * HH + scol];
    const unsigned short* ga1 = &Xb[(size_t)(m0 + 64 + srow) * HH + scol];
    const unsigned short* gb0 = &Wt[(size_t)(n0 + srow) * HH + scol];
    const unsigned short* gb1 = &Wt[(size_t)(n0 + 64 + srow) * HH + scol];
    unsigned short* la = &As[w * 512];          // wave-uniform base (w*1024 bytes)
    unsigned short* lb = &Bs[w * 512];

    f32x4 acc[4][4] = {};   // [mi][ni]

    for (int kk = 0; kk < HH; kk += 32) {
        gl_lds16(ga0 + kk, la);
        gl_lds16(ga1 + kk, la + 2048);
        gl_lds16(gb0 + kk, lb);
        gl_lds16(gb1 + kk, lb + 2048);
        __syncthreads();   // drains vmcnt (global_load_lds) before ds_read

        bf16x8 a[4], b[4];
#pragma unroll
        for (int i = 0; i < 4; i++) {
            a[i] = *(const bf16x8*)&As[(wm + i * 16 + lm) * 32 + lq * 8];
            b[i] = *(const bf16x8*)&Bs[(wn + i * 16 + lm) * 32 + lq * 8];
        }
#pragma unroll
        for (int mi = 0; mi < 4; mi++)
#pragma unroll
            for (int ni = 0; ni < 4; ni++)
                acc[mi][ni] = __builtin_amdgcn_mfma_f32_16x16x32_bf16(
                    a[mi], b[ni], acc[mi][ni], 0, 0, 0);
        __syncthreads();   // frags consumed before next-tile overwrite
    }

    // Epilogue (round-1/3-verified): bias + interleaved RoPE via shfl_xor pairing.
#pragma unroll
    for (int ni = 0; ni < 4; ni++) {
        int n = n0 + wn + ni * 16 + lm;         // 0..1535
        float bv = bias[n];
        int h = n >> 7;                          // head
        int c = n & 127;                         // channel in [0,128)
        int j = c & 63;                          // d-index
        int ii = j >> 1;                         // freq index
        bool isK = (c >= 64);
        unsigned short* dst = isK ? Kr : Qr;
#pragma unroll
        for (int mi = 0; mi < 4; mi++) {
#pragma unroll
            for (int r = 0; r < 4; r++) {
                int m = m0 + wm + mi * 16 + lq * 4 + r;   // 0..8191
                int l = m & (LL - 1);
                int bidx = m >> 9;
                float v = acc[mi][ni][r] + bv;
                float vp = __shfl_xor(v, 1, 64);          // partner n^1 == lane^1
                float2 sc = *(const float2*)&pe[l * 64 + 2 * ii]; // {sin, cos}
                float o = (j & 1) ? (v * sc.y + vp * sc.x) : (v * sc.y - vp * sc.x);
                size_t idx = ((size_t)(bidx * HEADS + h) * LL + l) * DD + j;
                dst[idx] = f2bf(o);
            }
        }
    }
}

// ------------- Kernel 3: logits = Q @ K^T, mask, /8 -------------
// Per (b,h): 512x512, K-dim 64. Block 128x128 tile, 4 waves (2x2), NO LDS
// (Q+K per bh = 128 KB, L1/L2-resident). Swapped MFMA: acc = mfma(Kfrag, Qfrag)
// -> D row (lq*4+r) = n, D col (lane&15) = m -> float4 stores along n.
// Fully-causal-masked blocks (n0+127 < m0) skip loads/MFMA: |dot| << ulp(1e12)/2
// so (dot*pm - (1-pm)*NEG - NEG) rounds identically with dot=0.
// 1-D grid of 3072 tiles + bijective XCD swizzle (3072 = 8 * 384): each XCD
// exclusively owns 24 consecutive bh -> 3 MB of Q/K panels resident in its 4 MB
// L2 instead of every panel replicated into all 8 XCD L2s.
__global__ __launch_bounds__(256) void k_gemm2(
    const unsigned short* __restrict__ Qr,
    const unsigned short* __restrict__ Kr,
    const int* __restrict__ mask,            // [B][L]
    float* __restrict__ out)                 // [B][HEADS][L][L]
{
    int hwid = blockIdx.x;
    int vid  = (hwid & 7) * 384 + (hwid >> 3);   // bijective over 3072
    int bh = vid >> 4;
    int b  = bh / HEADS;
    int ti = vid & 15;
    int m0 = (ti >> 2) * 128;
    int n0 = (ti & 3) * 128;
    int tid = threadIdx.x;
    int w  = tid >> 6;
    int ln = tid & 63;
    int lq = ln >> 4;
    int lm = ln & 15;
    int wm = (w & 1) * 64;
    int wn = (w >> 1) * 64;

    const unsigned short* Qb = Qr + (size_t)bh * LL * DD;
    const unsigned short* Kb = Kr + (size_t)bh * LL * DD;

    f32x4 acc[4][4] = {};   // [ni][mi]
    if (n0 + 127 >= m0) {   // tile touches the surviving (n >= m) region
#pragma unroll
        for (int kk = 0; kk < 64; kk += 32) {
            bf16x8 q[4], k[4];
#pragma unroll
            for (int i = 0; i < 4; i++) {
                q[i] = *(const bf16x8*)&Qb[(size_t)(m0 + wm + i * 16 + lm) * DD + kk + lq * 8];
                k[i] = *(const bf16x8*)&Kb[(size_t)(n0 + wn + i * 16 + lm) * DD + kk + lq * 8];
            }
#pragma unroll
            for (int ni = 0; ni < 4; ni++)
#pragma unroll
                for (int mi = 0; mi < 4; mi++)
                    acc[ni][mi] = __builtin_amdgcn_mfma_f32_16x16x32_bf16(
                        k[ni], q[mi], acc[ni][mi], 0, 0, 0);
        }
    }

#pragma unroll
    for (int ni = 0; ni < 4; ni++) {
        int nb = n0 + wn + ni * 16 + lq * 4;            // 4 consecutive n in regs
        int4 mv = *(const int4*)&mask[b * LL + nb];     // 16B-aligned
#pragma unroll
        for (int mi = 0; mi < 4; mi++) {
            int m = m0 + wm + mi * 16 + lm;
            f32x4 o;
#pragma unroll
            for (int r = 0; r < 4; r++) {
                int n = nb + r;
                float pm = (float)((&mv.x)[r]);
                float dot = acc[ni][mi][r];
                o[r] = (dot * pm - (1.0f - pm) * NEGC - (n < m ? NEGC : 0.0f)) * 0.125f;
            }
            *(f32x4*)&out[((size_t)bh * LL + m) * LL + nb] = o;
        }
    }
}

extern "C" void kernel_launch(void* const* d_in, const int* in_sizes, int n_in,
                              void* d_out, int out_size, void* d_ws, size_t ws_size,
                              hipStream_t stream) {
    const float* X    = (const float*)d_in[0];   // (16,512,1024)
    const int*   mask = (const int*)d_in[1];     // (16,512)
    const float* W    = (const float*)d_in[2];   // (1024,1536)
    const float* bias = (const float*)d_in[3];   // (1536,)
    const float* pe   = (const float*)d_in[4];   // (512,64)
    float* out = (float*)d_out;

    char* ws = (char*)d_ws;
    unsigned short* Xb = (unsigned short*)ws;                                // 16.78 MB
    unsigned short* Wt = (unsigned short*)(ws + 16777216);                   // 3.15 MB
    unsigned short* Qr = (unsigned short*)(ws + 16777216 + 3145728);         // 12.58 MB
    unsigned short* Kr = Qr + (size_t)BB * HEADS * LL * DD;                  // 12.58 MB

    // 1) fused prep: convert X + transpose/convert W
    k_prep<<<dim3(8192 + 1536), dim3(256), 0, stream>>>(X, Xb, W, Wt);
    // 2) GEMM1 + bias + RoPE -> Qr, Kr  (128x128, gload_lds, XCD swizzle, shfl RoPE)
    k_gemm1_rope<<<dim3(N1 / 128, M1 / 128), dim3(256), 0, stream>>>(Xb, Wt, bias, pe, Qr, Kr);
    // 3) GEMM2 + mask + scale -> out  (128x128, no-LDS, causal skip, XCD swizzle)
    k_gemm2<<<dim3(3072), dim3(256), 0, stream>>>(Qr, Kr, mask, out);
}

// Round 10
// 305.352 us; speedup vs baseline: 1.1095x; 1.0366x over previous
//
#include <hip/hip_runtime.h>

// Problem constants (GlobalPointer: B=16, L=512, H=1024, HEADS=12, D=64)
#define BB 16
#define LL 512
#define HH 1024
#define HEADS 12
#define DD 64
#define N1 1536   // HEADS * 2 * DD
#define M1 8192   // BB * LL
#define NEGC 1e12f

typedef short bf16x8 __attribute__((ext_vector_type(8)));
typedef float f32x4 __attribute__((ext_vector_type(4)));

typedef const __attribute__((address_space(1))) void* as1cvp;
typedef __attribute__((address_space(3))) void* as3vp;

__device__ __forceinline__ unsigned short f2bf(float f) {
    union { float f; unsigned int u; } v; v.f = f;
    unsigned int u = v.u;
    return (unsigned short)((u + 0x7fffu + ((u >> 16) & 1u)) >> 16);
}

// async global -> LDS, 16B per lane; lds dest = wave-uniform base + lane*16
__device__ __forceinline__ void gl_lds16(const void* g, void* l) {
    __builtin_amdgcn_global_load_lds((as1cvp)g, (as3vp)l, 16, 0, 0);
}

// ---------------- Kernel 1 (fused prep): X->bf16  +  W transpose->bf16 ----------------
// blocks [0, 8192): convert X (8192*1024 fp32, 4 elems/thread)
// blocks [8192, 9728): transpose W 32x32 tiles (48 n-blocks x 32 k-blocks)
__global__ __launch_bounds__(256) void k_prep(const float* __restrict__ X,
                                              unsigned short* __restrict__ Xb,
                                              const float* __restrict__ W,
                                              unsigned short* __restrict__ Wt) {
    __shared__ float tile[32][33];
    int blk = blockIdx.x;
    int tid = threadIdx.x;
    if (blk < 8192) {
        int i = blk * 256 + tid;          // exactly M1*HH/4 = 8192*256
        float4 v = ((const float4*)X)[i];
        ushort4 o;
        o.x = f2bf(v.x); o.y = f2bf(v.y); o.z = f2bf(v.z); o.w = f2bf(v.w);
        ((ushort4*)Xb)[i] = o;
    } else {
        int bi = blk - 8192;              // 0..1535
        int n0 = (bi % 48) * 32;
        int k0 = (bi / 48) * 32;
        int tx = tid & 31;                // 0..31
        int ty = tid >> 5;                // 0..7
#pragma unroll
        for (int i = 0; i < 4; i++) {
            int k = ty + i * 8;
            tile[k][tx] = W[(size_t)(k0 + k) * N1 + n0 + tx];
        }
        __syncthreads();
#pragma unroll
        for (int i = 0; i < 4; i++) {
            int n = ty + i * 8;
            Wt[(size_t)(n0 + n) * HH + k0 + tx] = f2bf(tile[tx][n]);
        }
    }
}

// ------------- Kernel 2: C = Xb @ Wt^T (+bias, RoPE) -> Qr, Kr (bf16) -------------
// 2-phase double-buffered pipeline (T3-minimum recipe):
//   stage(tile0->buf0); sync;
//   loop: stage(tile t+1 -> buf p^1) BEFORE compute; ds_read buf p; MFMA;
//         ONE __syncthreads() per K-step (vmcnt(0): prefetch landed;
//         lgkmcnt(0): this tile's reads precede its next overwrite).
// LDS staging layout per 8192-byte buffer (LINEAR, required by global_load_lds):
//   wave w, first 64 rows:  bytes [w*1024,      w*1024+1024)
//   wave w, second 64 rows: bytes [4096+w*1024, 4096+w*1024+1024)
// *** R6/R7 NaN root cause: second-half offset was +2048 BYTES (a char*/short*
// unit typo; must be +4096 bytes = +2048 elems) -> waves collided and bytes
// [4096,8192) were never written. Fixed here; schedule unchanged from R7. ***
__global__ __launch_bounds__(256) void k_gemm1_rope(
    const unsigned short* __restrict__ Xb,   // [8192][1024]
    const unsigned short* __restrict__ Wt,   // [1536][1024]
    const float* __restrict__ bias,          // [1536]
    const float* __restrict__ pe,            // [512][64]  pe[l][2i]=sin, [2i+1]=cos
    unsigned short* __restrict__ Qr,         // [B*HEADS*512][64]
    unsigned short* __restrict__ Kr)
{
    __shared__ __align__(16) unsigned short As[2 * 128 * 32];  // 2 bufs x 8 KB
    __shared__ __align__(16) unsigned short Bs[2 * 128 * 32];  // 2 bufs x 8 KB
    // bijective XCD swizzle (768 = 8 * 96)
    int hwid = blockIdx.x + gridDim.x * blockIdx.y;   // hardware dispatch order
    int vid  = (hwid & 7) * 96 + (hwid >> 3);
    int m0 = (vid / 12) * 128;
    int n0 = (vid % 12) * 128;
    int tid = threadIdx.x;
    int w  = tid >> 6;
    int ln = tid & 63;
    int lq = ln >> 4;
    int lm = ln & 15;
    int wm = (w & 1) * 64;
    int wn = (w >> 1) * 64;

    // staging: thread covers byte tid*16 (+4096 for second half) of each 8KB tile
    int srow = tid >> 2;            // 0..63
    int scol = (tid & 3) * 8;       // 0,8,16,24
    const unsigned short* ga0 = &Xb[(size_t)(m0 + srow) * HH + scol];
    const unsigned short* ga1 = &Xb[(size_t)(m0 + 64 + srow) * HH + scol];
    const unsigned short* gb0 = &Wt[(size_t)(n0 + srow) * HH + scol];
    const unsigned short* gb1 = &Wt[(size_t)(n0 + 64 + srow) * HH + scol];

    f32x4 acc[4][4] = {};   // [mi][ni]

    // prologue: stage tile 0 into buf 0, then full sync (loads landed)
    {
        char* la = (char*)As + w * 1024;
        char* lb = (char*)Bs + w * 1024;
        gl_lds16(ga0, la);
        gl_lds16(ga1, la + 4096);   // BYTES: second 64-row half starts at +4096
        gl_lds16(gb0, lb);
        gl_lds16(gb1, lb + 4096);
    }
    __syncthreads();

    for (int t = 0; t < 32; t++) {
        int p = t & 1;
        if (t < 31) {   // issue next-tile prefetch BEFORE compute; latency hides
            int kk2 = (t + 1) * 32;
            char* la = (char*)As + (p ^ 1) * 8192 + w * 1024;
            char* lb = (char*)Bs + (p ^ 1) * 8192 + w * 1024;
            gl_lds16(ga0 + kk2, la);
            gl_lds16(ga1 + kk2, la + 4096);   // BYTES (R6/R7 bug was +2048)
            gl_lds16(gb0 + kk2, lb);
            gl_lds16(gb1 + kk2, lb + 4096);
        }

        const unsigned short* Ab = As + p * 4096;   // elem offset (8 KB/buf)
        const unsigned short* Bb = Bs + p * 4096;
        bf16x8 a[4], b[4];
#pragma unroll
        for (int i = 0; i < 4; i++) {
            a[i] = *(const bf16x8*)&Ab[(wm + i * 16 + lm) * 32 + lq * 8];
            b[i] = *(const bf16x8*)&Bb[(wn + i * 16 + lm) * 32 + lq * 8];
        }
#pragma unroll
        for (int mi = 0; mi < 4; mi++)
#pragma unroll
            for (int ni = 0; ni < 4; ni++)
                acc[mi][ni] = __builtin_amdgcn_mfma_f32_16x16x32_bf16(
                    a[mi], b[ni], acc[mi][ni], 0, 0, 0);

        // ONE sync per K-step: drains prefetch (vmcnt) so buf p^1 is ready for
        // t+1, and drains lgkmcnt so this tile's reads precede its overwrite.
        __syncthreads();
    }

    // Epilogue (round-1/3/5-verified): bias + interleaved RoPE via shfl_xor.
#pragma unroll
    for (int ni = 0; ni < 4; ni++) {
        int n = n0 + wn + ni * 16 + lm;         // 0..1535
        float bv = bias[n];
        int h = n >> 7;                          // head
        int c = n & 127;                         // channel in [0,128)
        int j = c & 63;                          // d-index
        int ii = j >> 1;                         // freq index
        bool isK = (c >= 64);
        unsigned short* dst = isK ? Kr : Qr;
#pragma unroll
        for (int mi = 0; mi < 4; mi++) {
#pragma unroll
            for (int r = 0; r < 4; r++) {
                int m = m0 + wm + mi * 16 + lq * 4 + r;   // 0..8191
                int l = m & (LL - 1);
                int bidx = m >> 9;
                float v = acc[mi][ni][r] + bv;
                float vp = __shfl_xor(v, 1, 64);          // partner n^1 == lane^1
                float2 sc = *(const float2*)&pe[l * 64 + 2 * ii]; // {sin, cos}
                float o = (j & 1) ? (v * sc.y + vp * sc.x) : (v * sc.y - vp * sc.x);
                size_t idx = ((size_t)(bidx * HEADS + h) * LL + l) * DD + j;
                dst[idx] = f2bf(o);
            }
        }
    }
}

// ------------- Kernel 3: logits = Q @ K^T, mask, /8 -------------
// Per (b,h): 512x512, K-dim 64. Block 128x128 tile, 4 waves (2x2), NO LDS
// (Q+K per bh = 128 KB, L1/L2-resident). Swapped MFMA: acc = mfma(Kfrag, Qfrag)
// -> D row (lq*4+r) = n, D col (lane&15) = m -> float4 stores along n.
// Fully-causal-masked blocks (n0+127 < m0) skip loads/MFMA: |dot| << ulp(1e12)/2
// so (dot*pm - (1-pm)*NEG - NEG) rounds identically with dot=0.
// 1-D grid of 3072 tiles + bijective XCD swizzle (3072 = 8 * 384): each XCD
// exclusively owns 24 consecutive bh -> 3 MB of Q/K panels resident in its 4 MB L2.
__global__ __launch_bounds__(256) void k_gemm2(
    const unsigned short* __restrict__ Qr,
    const unsigned short* __restrict__ Kr,
    const int* __restrict__ mask,            // [B][L]
    float* __restrict__ out)                 // [B][HEADS][L][L]
{
    int hwid = blockIdx.x;
    int vid  = (hwid & 7) * 384 + (hwid >> 3);   // bijective over 3072
    int bh = vid >> 4;
    int b  = bh / HEADS;
    int ti = vid & 15;
    int m0 = (ti >> 2) * 128;
    int n0 = (ti & 3) * 128;
    int tid = threadIdx.x;
    int w  = tid >> 6;
    int ln = tid & 63;
    int lq = ln >> 4;
    int lm = ln & 15;
    int wm = (w & 1) * 64;
    int wn = (w >> 1) * 64;

    const unsigned short* Qb = Qr + (size_t)bh * LL * DD;
    const unsigned short* Kb = Kr + (size_t)bh * LL * DD;

    f32x4 acc[4][4] = {};   // [ni][mi]
    if (n0 + 127 >= m0) {   // tile touches the surviving (n >= m) region
#pragma unroll
        for (int kk = 0; kk < 64; kk += 32) {
            bf16x8 q[4], k[4];
#pragma unroll
            for (int i = 0; i < 4; i++) {
                q[i] = *(const bf16x8*)&Qb[(size_t)(m0 + wm + i * 16 + lm) * DD + kk + lq * 8];
                k[i] = *(const bf16x8*)&Kb[(size_t)(n0 + wn + i * 16 + lm) * DD + kk + lq * 8];
            }
#pragma unroll
            for (int ni = 0; ni < 4; ni++)
#pragma unroll
                for (int mi = 0; mi < 4; mi++)
                    acc[ni][mi] = __builtin_amdgcn_mfma_f32_16x16x32_bf16(
                        k[ni], q[mi], acc[ni][mi], 0, 0, 0);
        }
    }

#pragma unroll
    for (int ni = 0; ni < 4; ni++) {
        int nb = n0 + wn + ni * 16 + lq * 4;            // 4 consecutive n in regs
        int4 mv = *(const int4*)&mask[b * LL + nb];     // 16B-aligned
#pragma unroll
        for (int mi = 0; mi < 4; mi++) {
            int m = m0 + wm + mi * 16 + lm;
            f32x4 o;
#pragma unroll
            for (int r = 0; r < 4; r++) {
                int n = nb + r;
                float pm = (float)((&mv.x)[r]);
                float dot = acc[ni][mi][r];
                o[r] = (dot * pm - (1.0f - pm) * NEGC - (n < m ? NEGC : 0.0f)) * 0.125f;
            }
            *(f32x4*)&out[((size_t)bh * LL + m) * LL + nb] = o;
        }
    }
}

extern "C" void kernel_launch(void* const* d_in, const int* in_sizes, int n_in,
                              void* d_out, int out_size, void* d_ws, size_t ws_size,
                              hipStream_t stream) {
    const float* X    = (const float*)d_in[0];   // (16,512,1024)
    const int*   mask = (const int*)d_in[1];     // (16,512)
    const float* W    = (const float*)d_in[2];   // (1024,1536)
    const float* bias = (const float*)d_in[3];   // (1536,)
    const float* pe   = (const float*)d_in[4];   // (512,64)
    float* out = (float*)d_out;

    char* ws = (char*)d_ws;
    unsigned short* Xb = (unsigned short*)ws;                                // 16.78 MB
    unsigned short* Wt = (unsigned short*)(ws + 16777216);                   // 3.15 MB
    unsigned short* Qr = (unsigned short*)(ws + 16777216 + 3145728);         // 12.58 MB
    unsigned short* Kr = Qr + (size_t)BB * HEADS * LL * DD;                  // 12.58 MB

    // 1) fused prep: convert X + transpose/convert W
    k_prep<<<dim3(8192 + 1536), dim3(256), 0, stream>>>(X, Xb, W, Wt);
    // 2) GEMM1 + bias + RoPE -> Qr, Kr  (128x128, 2-phase dbuf, offset fix)
    k_gemm1_rope<<<dim3(N1 / 128, M1 / 128), dim3(256), 0, stream>>>(Xb, Wt, bias, pe, Qr, Kr);
    // 3) GEMM2 + mask + scale -> out  (128x128, no-LDS, causal skip, XCD swizzle)
    k_gemm2<<<dim3(3072), dim3(256), 0, stream>>>(Qr, Kr, mask, out);
}